// Round 15
// baseline (518.938 us; speedup 1.0000x reference)
//
#include <hip/hip_runtime.h>
#include <stdint.h>

// E=8, C=1024, H=2048, I=4096.  gate_up = X@Wgu; act = silu(g)*u; out = act@Wd
// Round 15: R13 data paths (fused B transpose+cvt, swz8, 16x16x32 MFMA,
// gate|up interleave, XCD chunking) with the m201-style FINE-GRAINED
// 4-phase x 2-barrier schedule (m196: the per-phase interleave is the lever):
//   P0: ds_read af(kk0)x8 + b(n01)x2 | stageA(t+1) pc0,1 | bar | lgkm0 | 16 MFMA | bar
//   P1: ds_read b(n23)x2             | stageA(t+1) pc2,3 | bar | lgkm0 | 16 MFMA | bar
//   P2: ds_read af(kk1)x8 + b(n01)x2 | vmcnt(4)+cvtWriteB(t+1) | bar | lgkm0 | 16 MFMA | bar
//   P3: ds_read b(n23)x2             | loadB8(t+2) | bar | lgkm0 | 16 MFMA
//       | boundary: vmcnt(8) [A(t+1) done, B(t+2) in flight] + lgkm0 + bar
// FIFO ledger: B8(t+1) issued tile t-1 P3 (oldest) -> A4(t+1) at P0/P1 ->
// B8(t+2) at P3. P2's vmcnt(4) completes exactly B8(t+1); boundary vmcnt(8)
// completes A4(t+1), leaves B8(t+2).

#define E_  8
#define C_  1024
#define H_  2048
#define I_  4096
#define N1_ 8192   // 2*I

typedef __bf16 bf16x8 __attribute__((ext_vector_type(8)));
typedef float  f32x4  __attribute__((ext_vector_type(4)));

typedef __attribute__((address_space(3))) unsigned       lds_uint;
typedef const __attribute__((address_space(1))) unsigned glob_uint;

__device__ __forceinline__ void gload_lds16(const void* g, void* l) {
    __builtin_amdgcn_global_load_lds((glob_uint*)g, (lds_uint*)l, 16, 0, 0);
}

__device__ __forceinline__ unsigned short f2bf(float f) {
    union { float f; unsigned u; } v; v.f = f;
    unsigned u = v.u;
    return (unsigned short)((u + 0x7FFFu + ((u >> 16) & 1u)) >> 16);  // RNE
}

__device__ __forceinline__ unsigned swz8(unsigned row) {
    return ((row ^ (row >> 2)) & 7u) << 4;   // 16B-slot XOR constant
}

#define SBAR0 __builtin_amdgcn_sched_barrier(0)
#define MFMA_ __builtin_amdgcn_mfma_f32_16x16x32_bf16

// ---------------- elementwise fp32 -> bf16 (X only) ----------------
__global__ void k_convert(const float* __restrict__ src,
                          unsigned short* __restrict__ dst, int n8) {
    int idx = blockIdx.x * blockDim.x + threadIdx.x;
    int stride = gridDim.x * blockDim.x;
    for (int i = idx; i < n8; i += stride) {
        const float4* s = reinterpret_cast<const float4*>(src + (size_t)i * 8);
        float4 a = s[0], b = s[1];
        ushort4 lo, hi;
        lo.x = f2bf(a.x); lo.y = f2bf(a.y); lo.z = f2bf(a.z); lo.w = f2bf(a.w);
        hi.x = f2bf(b.x); hi.y = f2bf(b.y); hi.z = f2bf(b.z); hi.w = f2bf(b.w);
        ushort4* d = reinterpret_cast<ushort4*>(dst + (size_t)i * 8);
        d[0] = lo; d[1] = hi;
    }
}

// ---------------- staging helpers (identical to round 13) ----------------
template<int LD>
__device__ __forceinline__ void stageA(const char* __restrict__ gtile,
                                       char* ldst, int j, int tid, int wave) {
    unsigned p   = (unsigned)(j * 8192 + tid * 16);
    unsigned row = p >> 7;
    unsigned kb  = (p & 127u) ^ swz8(row);
    const char* gp = gtile + (size_t)row * LD + kb;
    void* lp = ldst + j * 8192 + wave * 1024;   // wave-uniform base
    gload_lds16(gp, lp);
}

__device__ __forceinline__ const bf16x8* frag128(const char* tile, int row, int kb) {
    unsigned phys = (unsigned)(row * 128) + ((unsigned)kb ^ swz8((unsigned)row));
    return reinterpret_cast<const bf16x8*>(tile + phys);
}

template<int LDB>
__device__ __forceinline__ void loadB8(const char* __restrict__ gcol, int kt,
                                       float4 (&bk)[8]) {
    const char* p = gcol + (size_t)(kt * 64) * LDB;
    #pragma unroll
    for (int i = 0; i < 8; ++i)
        bk[i] = *reinterpret_cast<const float4*>(p + (size_t)i * LDB);
}

__device__ __forceinline__ void cvtWriteB(char* bB, const float4 (&bk)[8],
                                          int rg, int kg8) {
    const float* f = reinterpret_cast<const float*>(&bk[0]);
    #pragma unroll
    for (int j = 0; j < 4; ++j) {
        unsigned u[4];
        #pragma unroll
        for (int p2 = 0; p2 < 4; ++p2) {
            float lo = f[(2 * p2) * 4 + j];
            float hi = f[(2 * p2 + 1) * 4 + j];
            asm("v_cvt_pk_bf16_f32 %0, %1, %2" : "=v"(u[p2]) : "v"(lo), "v"(hi));
        }
        unsigned q = (unsigned)(rg * 4 + j);
        unsigned phys = q * 128 + (((unsigned)kg8 * 16) ^ swz8(q));
        *reinterpret_cast<uint4*>(bB + phys) = make_uint4(u[0], u[1], u[2], u[3]);
    }
}

// MODE 0: gemm1 (B=Wgu native [H][2I], gate|up 16-col interleave, silu -> bf16)
// MODE 1: gemm2 (B=Wd native [I][H], f32 out)
template<int LDA, int LDB, int NT, int BMG, int BNG, int MODE>
__global__ __launch_bounds__(512, 2) void k_gemm_f(
    const unsigned short* __restrict__ A,
    const float* __restrict__ B,
    void* __restrict__ Cout,
    size_t sA, size_t sB) {
    __shared__ char lds[131072];   // 2 bufs x (A 32K | B 32K)

    const int tid = threadIdx.x, lane = tid & 63, wave = tid >> 6;
    const int wm = wave >> 2, wn = wave & 3;
    const int kg = lane >> 4, r = lane & 15;
    const int rg = tid & 63, kg8 = tid >> 6;   // B-staging role

    // flattened grid, bijective XCD chunking (gridDim.x % 8 == 0), bm innermost
    unsigned flat = blockIdx.x;
    unsigned cpx = gridDim.x >> 3;
    unsigned nid = (flat & 7u) * cpx + (flat >> 3);
    const int bm = nid % BMG;
    const int bn = (nid / BMG) % BNG;
    const int e  = nid / (BMG * BNG);

    const char* gA = (const char*)(A + sA * e) + (size_t)(bm * 256) * LDA;
    size_t colstart;
    if constexpr (MODE == 0)
        colstart = (size_t)(bn * 128 + ((rg >> 4) & 3) * 32 + ((rg >> 2) & 1) * 16
                            + (rg & 3) * 4)
                 + (((rg >> 3) & 1) ? (size_t)I_ : (size_t)0);
    else
        colstart = (size_t)(bn * 256 + rg * 4);
    const char* gBcol = (const char*)B + sB * e + colstart * 4
                      + (size_t)kg8 * 8 * LDB;

    float4 bk[8];

    // ---------------- prologue ----------------
    loadB8<LDB>(gBcol, 0, bk);          // B(0) f32 regs [8]
    SBAR0;
    stageA<LDA>(gA, lds, 0, tid, wave); // A(0) -> buf0 [4]
    stageA<LDA>(gA, lds, 1, tid, wave);
    stageA<LDA>(gA, lds, 2, tid, wave);
    stageA<LDA>(gA, lds, 3, tid, wave);
    SBAR0;
    asm volatile("s_waitcnt vmcnt(4)" ::: "memory");   // B(0) done, A(0) in flight
    SBAR0;
    cvtWriteB(lds + 32768, bk, rg, kg8);
    SBAR0;
    loadB8<LDB>(gBcol, 1, bk);          // B(1) prefetch [8]
    SBAR0;
    asm volatile("s_waitcnt vmcnt(8)" ::: "memory");   // A(0) done; B(1) in flight
    asm volatile("s_waitcnt lgkmcnt(0)" ::: "memory");
    SBAR0;
    __builtin_amdgcn_s_barrier();
    SBAR0;

    f32x4 acc[8][4] = {};

    for (int t = 0; t < NT; ++t) {
        const char* Ab = lds + (t & 1) * 65536;
        const char* Bb = Ab + 32768;
        char* nA = lds + ((t + 1) & 1) * 65536;
        char* nB = nA + 32768;
        const char* gAn = gA + (size_t)(t + 1) * 128;
        const bool hs1 = (t + 1) < NT, hs2 = (t + 2) < NT;

        bf16x8 af[8], b0[2], bg[2];

        // ======== phase 0: kk0, n0-1 | stageA pc0,1 ========
        #pragma unroll
        for (int m = 0; m < 8; ++m)
            af[m] = *frag128(Ab, wm * 128 + m * 16 + r, kg * 16);
        #pragma unroll
        for (int n = 0; n < 2; ++n)
            b0[n] = *frag128(Bb, wn * 64 + n * 16 + r, kg * 16);
        if (hs1) { stageA<LDA>(gAn, nA, 0, tid, wave);
                   stageA<LDA>(gAn, nA, 1, tid, wave); }
        SBAR0;
        __builtin_amdgcn_s_barrier();
        asm volatile("s_waitcnt lgkmcnt(0)" ::: "memory");
        SBAR0;
        __builtin_amdgcn_s_setprio(1);
        #pragma unroll
        for (int m = 0; m < 8; ++m) {
            acc[m][0] = MFMA_(af[m], b0[0], acc[m][0], 0, 0, 0);
            acc[m][1] = MFMA_(af[m], b0[1], acc[m][1], 0, 0, 0);
        }
        __builtin_amdgcn_s_setprio(0);
        SBAR0;
        __builtin_amdgcn_s_barrier();
        SBAR0;

        // ======== phase 1: kk0, n2-3 | stageA pc2,3 ========
        #pragma unroll
        for (int n = 0; n < 2; ++n)
            bg[n] = *frag128(Bb, wn * 64 + 32 + n * 16 + r, kg * 16);
        if (hs1) { stageA<LDA>(gAn, nA, 2, tid, wave);
                   stageA<LDA>(gAn, nA, 3, tid, wave); }
        SBAR0;
        __builtin_amdgcn_s_barrier();
        asm volatile("s_waitcnt lgkmcnt(0)" ::: "memory");
        SBAR0;
        __builtin_amdgcn_s_setprio(1);
        #pragma unroll
        for (int m = 0; m < 8; ++m) {
            acc[m][2] = MFMA_(af[m], bg[0], acc[m][2], 0, 0, 0);
            acc[m][3] = MFMA_(af[m], bg[1], acc[m][3], 0, 0, 0);
        }
        __builtin_amdgcn_s_setprio(0);
        SBAR0;
        __builtin_amdgcn_s_barrier();
        SBAR0;

        // ======== phase 2: kk1, n0-1 | vmcnt(4)+cvtWriteB(t+1) ========
        #pragma unroll
        for (int m = 0; m < 8; ++m)
            af[m] = *frag128(Ab, wm * 128 + m * 16 + r, 64 + kg * 16);
        #pragma unroll
        for (int n = 0; n < 2; ++n)
            b0[n] = *frag128(Bb, wn * 64 + n * 16 + r, 64 + kg * 16);
        if (hs1) {
            asm volatile("s_waitcnt vmcnt(4)" ::: "memory");  // B8(t+1) done (A4 newer)
            SBAR0;
            cvtWriteB(nB, bk, rg, kg8);
        }
        SBAR0;
        __builtin_amdgcn_s_barrier();
        asm volatile("s_waitcnt lgkmcnt(0)" ::: "memory");
        SBAR0;
        __builtin_amdgcn_s_setprio(1);
        #pragma unroll
        for (int m = 0; m < 8; ++m) {
            acc[m][0] = MFMA_(af[m], b0[0], acc[m][0], 0, 0, 0);
            acc[m][1] = MFMA_(af[m], b0[1], acc[m][1], 0, 0, 0);
        }
        __builtin_amdgcn_s_setprio(0);
        SBAR0;
        __builtin_amdgcn_s_barrier();
        SBAR0;

        // ======== phase 3: kk1, n2-3 | loadB8(t+2) | boundary ========
        #pragma unroll
        for (int n = 0; n < 2; ++n)
            bg[n] = *frag128(Bb, wn * 64 + 32 + n * 16 + r, 64 + kg * 16);
        if (hs2) { loadB8<LDB>(gBcol, t + 2, bk); }
        SBAR0;
        __builtin_amdgcn_s_barrier();
        asm volatile("s_waitcnt lgkmcnt(0)" ::: "memory");
        SBAR0;
        __builtin_amdgcn_s_setprio(1);
        #pragma unroll
        for (int m = 0; m < 8; ++m) {
            acc[m][2] = MFMA_(af[m], bg[0], acc[m][2], 0, 0, 0);
            acc[m][3] = MFMA_(af[m], bg[1], acc[m][3], 0, 0, 0);
        }
        __builtin_amdgcn_s_setprio(0);
        SBAR0;
        if (hs1) {
            if (hs2) asm volatile("s_waitcnt vmcnt(8)" ::: "memory");  // A4(t+1) done
            else     asm volatile("s_waitcnt vmcnt(0)" ::: "memory");
            asm volatile("s_waitcnt lgkmcnt(0)" ::: "memory");
            SBAR0;
            __builtin_amdgcn_s_barrier();
            SBAR0;
        }
    }

    // ---------------- epilogue ----------------
    const int row0 = bm * 256 + wm * 128 + kg * 4;   // + m*16 + j
    if constexpr (MODE == 0) {
        unsigned short* act = (unsigned short*)Cout + (size_t)e * C_ * I_;
        const int col0 = bn * 128 + wn * 32 + r;
        #pragma unroll
        for (int m = 0; m < 8; ++m)
            #pragma unroll
            for (int n = 0; n < 2; ++n)
                #pragma unroll
                for (int j = 0; j < 4; ++j) {
                    float g = acc[m][n][j], u = acc[m][n + 2][j];
                    float s = g / (1.0f + __expf(-g)) * u;
                    act[(size_t)(row0 + m * 16 + j) * I_ + col0 + n * 16] = f2bf(s);
                }
    } else {
        float* o = (float*)Cout + (size_t)e * C_ * H_;
        const int col0 = bn * 256 + wn * 64 + r;
        #pragma unroll
        for (int m = 0; m < 8; ++m)
            #pragma unroll
            for (int n = 0; n < 4; ++n)
                #pragma unroll
                for (int j = 0; j < 4; ++j)
                    o[(size_t)(row0 + m * 16 + j) * H_ + col0 + n * 16] = acc[m][n][j];
    }
}

// ---------------- launch ----------------
extern "C" void kernel_launch(void* const* d_in, const int* in_sizes, int n_in,
                              void* d_out, int out_size, void* d_ws, size_t ws_size,
                              hipStream_t stream) {
    const float* hs  = (const float*)d_in[0];   // [E][C][H]
    const float* wgu = (const float*)d_in[1];   // [E][H][2I]
    const float* wd  = (const float*)d_in[2];   // [E][I][H]
    float* out = (float*)d_out;

    char* ws = (char*)d_ws;
    unsigned short* Xbf  = (unsigned short*)(ws);                 // 33,554,432 B
    unsigned short* actb = (unsigned short*)(ws + 33554432ull);   // 67,108,864 B

    k_convert<<<2048, 256, 0, stream>>>(hs, Xbf, E_ * C_ * H_ / 8);

    // GEMM1 (fused transpose+silu): X[EC][H] x Wgu native -> act bf16 [EC][I]
    // BM=256 (BMG=4), 128 act cols/block (BNG=32), NT=32 (BK=64). 1024 blocks.
    k_gemm_f<H_ * 2, N1_ * 4, H_ / 64, 4, 32, 0><<<dim3(1024), 512, 0, stream>>>(
        Xbf, wgu, actb, (size_t)C_ * H_, (size_t)H_ * N1_ * 4);

    // GEMM2 (fused transpose): act[EC][I] x Wd native -> out f32 [EC][H]
    // BM=256 (BMG=4), BN=256 (BNG=8), NT=64 (BK=64). 256 blocks.
    k_gemm_f<I_ * 2, H_ * 4, I_ / 64, 4, 8, 1><<<dim3(256), 512, 0, stream>>>(
        actb, wd, out, (size_t)C_ * I_, (size_t)I_ * H_ * 4);
}

// Round 16
// 470.678 us; speedup vs baseline: 1.1025x; 1.1025x over previous
//
#include <hip/hip_runtime.h>
#include <stdint.h>

// E=8, C=1024, H=2048, I=4096.  gate_up = X@Wgu; act = silu(g)*u; out = act@Wd
// Round 16: exactly R13 (best, 474us) with the intra-phase lgkmcnt(0)+
// sched_barrier pins REMOVED from the compute phases. All LDS reads and B
// reg loads are compiler-visible, so hipcc emits counted lgkmcnt and can
// pipeline phase p+1's ds_reads under phase p's MFMA tail (m97/m141: manual
// full-drain pins defeat this). Pins remain ONLY where the compiler cannot
// see the dependency: gload_lds->LDS (boundary vmcnt+barrier) and ds_write
// cross-wave visibility (boundary lgkm before barrier). Staging cluster and
// vmcnt FIFO ledger byte-identical to R13.

#define E_  8
#define C_  1024
#define H_  2048
#define I_  4096
#define N1_ 8192   // 2*I

typedef __bf16 bf16x8 __attribute__((ext_vector_type(8)));
typedef float  f32x4  __attribute__((ext_vector_type(4)));

typedef __attribute__((address_space(3))) unsigned       lds_uint;
typedef const __attribute__((address_space(1))) unsigned glob_uint;

__device__ __forceinline__ void gload_lds16(const void* g, void* l) {
    __builtin_amdgcn_global_load_lds((glob_uint*)g, (lds_uint*)l, 16, 0, 0);
}

__device__ __forceinline__ unsigned short f2bf(float f) {
    union { float f; unsigned u; } v; v.f = f;
    unsigned u = v.u;
    return (unsigned short)((u + 0x7FFFu + ((u >> 16) & 1u)) >> 16);  // RNE
}

__device__ __forceinline__ unsigned swz8(unsigned row) {
    return ((row ^ (row >> 2)) & 7u) << 4;   // 16B-slot XOR constant
}

#define SBAR0 __builtin_amdgcn_sched_barrier(0)
#define MFMA_ __builtin_amdgcn_mfma_f32_16x16x32_bf16

// ---------------- elementwise fp32 -> bf16 (X only) ----------------
__global__ void k_convert(const float* __restrict__ src,
                          unsigned short* __restrict__ dst, int n8) {
    int idx = blockIdx.x * blockDim.x + threadIdx.x;
    int stride = gridDim.x * blockDim.x;
    for (int i = idx; i < n8; i += stride) {
        const float4* s = reinterpret_cast<const float4*>(src + (size_t)i * 8);
        float4 a = s[0], b = s[1];
        ushort4 lo, hi;
        lo.x = f2bf(a.x); lo.y = f2bf(a.y); lo.z = f2bf(a.z); lo.w = f2bf(a.w);
        hi.x = f2bf(b.x); hi.y = f2bf(b.y); hi.z = f2bf(b.z); hi.w = f2bf(b.w);
        ushort4* d = reinterpret_cast<ushort4*>(dst + (size_t)i * 8);
        d[0] = lo; d[1] = hi;
    }
}

// ---------------- staging helpers (identical to round 13) ----------------
template<int LD>
__device__ __forceinline__ void stageA(const char* __restrict__ gtile,
                                       char* ldst, int j, int tid, int wave) {
    unsigned p   = (unsigned)(j * 8192 + tid * 16);
    unsigned row = p >> 7;
    unsigned kb  = (p & 127u) ^ swz8(row);
    const char* gp = gtile + (size_t)row * LD + kb;
    void* lp = ldst + j * 8192 + wave * 1024;   // wave-uniform base
    gload_lds16(gp, lp);
}

__device__ __forceinline__ const bf16x8* frag128(const char* tile, int row, int kb) {
    unsigned phys = (unsigned)(row * 128) + ((unsigned)kb ^ swz8((unsigned)row));
    return reinterpret_cast<const bf16x8*>(tile + phys);
}

template<int LDB>
__device__ __forceinline__ void loadB8(const char* __restrict__ gcol, int kt,
                                       float4 (&bk)[8]) {
    const char* p = gcol + (size_t)(kt * 64) * LDB;
    #pragma unroll
    for (int i = 0; i < 8; ++i)
        bk[i] = *reinterpret_cast<const float4*>(p + (size_t)i * LDB);
}

__device__ __forceinline__ void cvtWriteB(char* bB, const float4 (&bk)[8],
                                          int rg, int kg8) {
    const float* f = reinterpret_cast<const float*>(&bk[0]);
    #pragma unroll
    for (int j = 0; j < 4; ++j) {
        unsigned u[4];
        #pragma unroll
        for (int p2 = 0; p2 < 4; ++p2) {
            float lo = f[(2 * p2) * 4 + j];
            float hi = f[(2 * p2 + 1) * 4 + j];
            asm("v_cvt_pk_bf16_f32 %0, %1, %2" : "=v"(u[p2]) : "v"(lo), "v"(hi));
        }
        unsigned q = (unsigned)(rg * 4 + j);
        unsigned phys = q * 128 + (((unsigned)kg8 * 16) ^ swz8(q));
        *reinterpret_cast<uint4*>(bB + phys) = make_uint4(u[0], u[1], u[2], u[3]);
    }
}

// MODE 0: gemm1 (B=Wgu native [H][2I], gate|up 16-col interleave, silu -> bf16)
// MODE 1: gemm2 (B=Wd native [I][H], f32 out)
template<int LDA, int LDB, int NT, int BMG, int BNG, int MODE>
__global__ __launch_bounds__(512, 2) void k_gemm_f(
    const unsigned short* __restrict__ A,
    const float* __restrict__ B,
    void* __restrict__ Cout,
    size_t sA, size_t sB) {
    __shared__ char lds[131072];   // 2 bufs x (A 32K | B 32K)

    const int tid = threadIdx.x, lane = tid & 63, wave = tid >> 6;
    const int wm = wave >> 2, wn = wave & 3;
    const int kg = lane >> 4, r = lane & 15;
    const int rg = tid & 63, kg8 = tid >> 6;   // B-staging role

    // flattened grid, bijective XCD chunking (gridDim.x % 8 == 0), bm innermost
    unsigned flat = blockIdx.x;
    unsigned cpx = gridDim.x >> 3;
    unsigned nid = (flat & 7u) * cpx + (flat >> 3);
    const int bm = nid % BMG;
    const int bn = (nid / BMG) % BNG;
    const int e  = nid / (BMG * BNG);

    const char* gA = (const char*)(A + sA * e) + (size_t)(bm * 256) * LDA;
    size_t colstart;
    if constexpr (MODE == 0)
        colstart = (size_t)(bn * 128 + ((rg >> 4) & 3) * 32 + ((rg >> 2) & 1) * 16
                            + (rg & 3) * 4)
                 + (((rg >> 3) & 1) ? (size_t)I_ : (size_t)0);
    else
        colstart = (size_t)(bn * 256 + rg * 4);
    const char* gBcol = (const char*)B + sB * e + colstart * 4
                      + (size_t)kg8 * 8 * LDB;

    float4 bk[8];

    // ---------------- prologue (identical to R13) ----------------
    loadB8<LDB>(gBcol, 0, bk);
    SBAR0;
    asm volatile("s_waitcnt vmcnt(0)" ::: "memory");
    SBAR0;
    cvtWriteB(lds + 32768, bk, rg, kg8);
    SBAR0;
    stageA<LDA>(gA, lds, 0, tid, wave);
    stageA<LDA>(gA, lds, 1, tid, wave);
    stageA<LDA>(gA, lds, 2, tid, wave);
    stageA<LDA>(gA, lds, 3, tid, wave);
    SBAR0;
    loadB8<LDB>(gBcol, 1, bk);
    SBAR0;
    asm volatile("s_waitcnt vmcnt(8)" ::: "memory");   // A(0) done; B(1) in flight
    asm volatile("s_waitcnt lgkmcnt(0)" ::: "memory");
    SBAR0;
    __builtin_amdgcn_s_barrier();
    SBAR0;

    f32x4 acc[8][4] = {};

    for (int t = 0; t < NT; ++t) {
        const char* Ab = lds + (t & 1) * 65536;
        const char* Bb = Ab + 32768;
        char* nA = lds + ((t + 1) & 1) * 65536;
        char* nB = nA + 32768;
        const char* gAn = gA + (size_t)(t + 1) * 128;
        const bool hs1 = (t + 1) < NT, hs2 = (t + 2) < NT;

        bf16x8 af[8], b0[2], bg[2];

        // ---- tile-top staging block (pinned; identical to R13) ----
        if (hs1) {
            asm volatile("s_waitcnt vmcnt(0)" ::: "memory");   // bk = B(t+1) f32 done
            SBAR0;
            cvtWriteB(nB, bk, rg, kg8);
            SBAR0;
            stageA<LDA>(gAn, nA, 0, tid, wave);
            stageA<LDA>(gAn, nA, 1, tid, wave);
            stageA<LDA>(gAn, nA, 2, tid, wave);
            stageA<LDA>(gAn, nA, 3, tid, wave);
            SBAR0;
            if (hs2) { loadB8<LDB>(gBcol, t + 2, bk); SBAR0; }
        }

        // ---- compute phases: compiler-scheduled (no manual lgkm pins) ----
        // phase 0: kk0, n0-1
        #pragma unroll
        for (int m = 0; m < 8; ++m)
            af[m] = *frag128(Ab, wm * 128 + m * 16 + r, kg * 16);
        #pragma unroll
        for (int n = 0; n < 2; ++n)
            b0[n] = *frag128(Bb, wn * 64 + n * 16 + r, kg * 16);
        __builtin_amdgcn_s_setprio(1);
        #pragma unroll
        for (int m = 0; m < 8; ++m) {
            acc[m][0] = MFMA_(af[m], b0[0], acc[m][0], 0, 0, 0);
            acc[m][1] = MFMA_(af[m], b0[1], acc[m][1], 0, 0, 0);
        }
        __builtin_amdgcn_s_setprio(0);

        // phase 1: kk0, n2-3
        #pragma unroll
        for (int n = 0; n < 2; ++n)
            bg[n] = *frag128(Bb, wn * 64 + 32 + n * 16 + r, kg * 16);
        __builtin_amdgcn_s_setprio(1);
        #pragma unroll
        for (int m = 0; m < 8; ++m) {
            acc[m][2] = MFMA_(af[m], bg[0], acc[m][2], 0, 0, 0);
            acc[m][3] = MFMA_(af[m], bg[1], acc[m][3], 0, 0, 0);
        }
        __builtin_amdgcn_s_setprio(0);

        // phase 2: kk1, n0-1
        #pragma unroll
        for (int m = 0; m < 8; ++m)
            af[m] = *frag128(Ab, wm * 128 + m * 16 + r, 64 + kg * 16);
        #pragma unroll
        for (int n = 0; n < 2; ++n)
            b0[n] = *frag128(Bb, wn * 64 + n * 16 + r, 64 + kg * 16);
        __builtin_amdgcn_s_setprio(1);
        #pragma unroll
        for (int m = 0; m < 8; ++m) {
            acc[m][0] = MFMA_(af[m], b0[0], acc[m][0], 0, 0, 0);
            acc[m][1] = MFMA_(af[m], b0[1], acc[m][1], 0, 0, 0);
        }
        __builtin_amdgcn_s_setprio(0);

        // phase 3: kk1, n2-3
        #pragma unroll
        for (int n = 0; n < 2; ++n)
            bg[n] = *frag128(Bb, wn * 64 + 32 + n * 16 + r, 64 + kg * 16);
        __builtin_amdgcn_s_setprio(1);
        #pragma unroll
        for (int m = 0; m < 8; ++m) {
            acc[m][2] = MFMA_(af[m], bg[0], acc[m][2], 0, 0, 0);
            acc[m][3] = MFMA_(af[m], bg[1], acc[m][3], 0, 0, 0);
        }
        __builtin_amdgcn_s_setprio(0);

        // ---- boundary: counted drain (A(t+1) done, B(t+2) in flight) ----
        if (hs1) {
            SBAR0;
            if (hs2) asm volatile("s_waitcnt vmcnt(8)" ::: "memory");
            else     asm volatile("s_waitcnt vmcnt(0)" ::: "memory");
            asm volatile("s_waitcnt lgkmcnt(0)" ::: "memory");
            SBAR0;
            __builtin_amdgcn_s_barrier();
            SBAR0;
        }
    }

    // ---------------- epilogue ----------------
    const int row0 = bm * 256 + wm * 128 + kg * 4;   // + m*16 + j
    if constexpr (MODE == 0) {
        unsigned short* act = (unsigned short*)Cout + (size_t)e * C_ * I_;
        const int col0 = bn * 128 + wn * 32 + r;
        #pragma unroll
        for (int m = 0; m < 8; ++m)
            #pragma unroll
            for (int n = 0; n < 2; ++n)
                #pragma unroll
                for (int j = 0; j < 4; ++j) {
                    float g = acc[m][n][j], u = acc[m][n + 2][j];
                    float s = g / (1.0f + __expf(-g)) * u;
                    act[(size_t)(row0 + m * 16 + j) * I_ + col0 + n * 16] = f2bf(s);
                }
    } else {
        float* o = (float*)Cout + (size_t)e * C_ * H_;
        const int col0 = bn * 256 + wn * 64 + r;
        #pragma unroll
        for (int m = 0; m < 8; ++m)
            #pragma unroll
            for (int n = 0; n < 4; ++n)
                #pragma unroll
                for (int j = 0; j < 4; ++j)
                    o[(size_t)(row0 + m * 16 + j) * H_ + col0 + n * 16] = acc[m][n][j];
    }
}

// ---------------- launch ----------------
extern "C" void kernel_launch(void* const* d_in, const int* in_sizes, int n_in,
                              void* d_out, int out_size, void* d_ws, size_t ws_size,
                              hipStream_t stream) {
    const float* hs  = (const float*)d_in[0];   // [E][C][H]
    const float* wgu = (const float*)d_in[1];   // [E][H][2I]
    const float* wd  = (const float*)d_in[2];   // [E][I][H]
    float* out = (float*)d_out;

    char* ws = (char*)d_ws;
    unsigned short* Xbf  = (unsigned short*)(ws);                 // 33,554,432 B
    unsigned short* actb = (unsigned short*)(ws + 33554432ull);   // 67,108,864 B

    k_convert<<<2048, 256, 0, stream>>>(hs, Xbf, E_ * C_ * H_ / 8);

    // GEMM1 (fused transpose+silu): X[EC][H] x Wgu native -> act bf16 [EC][I]
    // BM=256 (BMG=4), 128 act cols/block (BNG=32), NT=32 (BK=64). 1024 blocks.
    k_gemm_f<H_ * 2, N1_ * 4, H_ / 64, 4, 32, 0><<<dim3(1024), 512, 0, stream>>>(
        Xbf, wgu, actb, (size_t)C_ * H_, (size_t)H_ * N1_ * 4);

    // GEMM2 (fused transpose): act[EC][I] x Wd native -> out f32 [EC][H]
    // BM=256 (BMG=4), BN=256 (BNG=8), NT=64 (BK=64). 256 blocks.
    k_gemm_f<I_ * 2, H_ * 4, I_ / 64, 4, 8, 1><<<dim3(256), 512, 0, stream>>>(
        actb, wd, out, (size_t)C_ * I_, (size_t)I_ * H_ * 4);
}